// Round 2
// baseline (177.936 us; speedup 1.0000x reference)
//
#include <hip/hip_runtime.h>

// LocalPredictor: 3x3 conv (32->128, center masked) + ReLU + 1x1 conv (128->32)
// B=8, k=32, H=W=256, HID=128. fp32 in/out (values bf16-exact) -> bf16 MFMA.
// v7 = v6 + occupancy/bank fixes:
//  - __launch_bounds__(256,4): VGPR cap 128 -> 4 blocks/CU -> entire 1024-block
//    grid resident in ONE round (v6's 3/CU left a 256-block straggler tail).
//    (v5's spills were at the 64-VGPR cap; 128 is mild.)
//  - h_lds stride 136 -> 132: epilogue1 ds_write_b16 banks go 4-way -> 2-way
//    (free); GEMM2 b128 reads stay at minimum coverage. LDS 39.4 -> 38.0 KB.
//  - everything else identical to the 174.9us harness-verified v6.

#define KC 32
#define HH 256
#define WW 256
#define HID 128
#define YS 8
#define ZROW 2640   // 66 cols * 40 (c-stride)
#define HSTR 132    // h_lds leading dim (shorts)

typedef __attribute__((ext_vector_type(8))) short short8;
typedef __attribute__((ext_vector_type(4))) float f32x4;

// LDS-visibility barrier WITHOUT vmcnt drain: global loads/stores stay in flight.
#define BARRIER() asm volatile("s_waitcnt lgkmcnt(0)\n\ts_barrier" ::: "memory")
#define SCHED_FENCE() asm volatile("" ::: "memory")

__device__ __forceinline__ unsigned short f2bf(float f) {
    union { float f; unsigned int i; } x; x.f = f;
    unsigned int r = x.i + 0x7FFFu + ((x.i >> 16) & 1u);  // RNE
    return (unsigned short)(r >> 16);
}

// pack 8 bf16-exact floats -> short8 (truncate = exact)
__device__ __forceinline__ short8 pack8(const float* v) {
    union { short8 s; unsigned int u[4]; } w;
    union { float f; unsigned int i; } uu[8];
#pragma unroll
    for (int j = 0; j < 8; ++j) uu[j].f = v[j];
#pragma unroll
    for (int k = 0; k < 4; ++k)
        w.u[k] = __builtin_amdgcn_perm(uu[2 * k + 1].i, uu[2 * k].i, 0x07060302u);
    return w.s;
}

// ws: w1t bf16[9*HID*KC] | w2t bf16[KC*HID].  w1t[p][d][c], c contiguous.
__global__ void prep_weights(const float* __restrict__ w1,
                             const float* __restrict__ w2,
                             unsigned short* __restrict__ w1t,
                             unsigned short* __restrict__ w2t) {
    int i = blockIdx.x * 256 + threadIdx.x;
    if (i < 9 * HID * KC) {
        int c = i & 31;
        int d = (i >> 5) & 127;
        int p = i >> 12;
        w1t[i] = f2bf(w1[d * (9 * KC) + c * 9 + p]);
    } else if (i < 9 * HID * KC + KC * HID) {
        int j = i - 9 * HID * KC;
        w2t[j] = f2bf(w2[j]);
    }
}

__global__ __launch_bounds__(256, 4) void local_pred_kernel(
    const float* __restrict__ zg,
    const unsigned short* __restrict__ w1t,
    const float* __restrict__ b1g,
    const unsigned short* __restrict__ w2t,
    const float* __restrict__ b2g,
    float* __restrict__ outg)
{
    __shared__ __attribute__((aligned(16))) unsigned short z_lds[4 * ZROW];      // 21120 B
    __shared__ __attribute__((aligned(16))) unsigned short h_lds[64 * HSTR];     // 16896 B
    __shared__ __attribute__((aligned(16))) unsigned short halo_lds[7 * 2 * 32]; //   896 B

    const int tid  = threadIdx.x;
    const int bidx = blockIdx.x;
    const int x0 = (bidx & 3) << 6;
    const int y0 = ((bidx >> 2) & 31) * YS;
    const int b  = bidx >> 7;

    const int l = tid & 63;       // staging x-lane
    const int o = tid >> 6;       // staging c-octet

    const int wave = tid >> 6;
    const int lane = tid & 63;
    const int lr = lane & 15;
    const int lq = lane >> 4;

    const float* zb = zg + (size_t)b * KC * HH * WW;

    // ---------------- prologue: sequential fenced rounds (low reg pressure) ----------------
    // main rows y0-1 .. y0+1
#pragma unroll
    for (int dy = 0; dy < 3; ++dy) {
        const int gy = y0 - 1 + dy;
        const bool ok = (unsigned)gy < (unsigned)HH;
        const int gyc = ok ? gy : 0;
        const float* p = zb + ((size_t)(o * 8) * HH + gyc) * WW + x0 + l;
        float t8[8];
#pragma unroll
        for (int j = 0; j < 8; ++j) t8[j] = ok ? p[(size_t)j * HH * WW] : 0.f;
        *(short8*)&z_lds[(dy * 66 + l + 1) * 40 + o * 8] = pack8(t8);
        SCHED_FENCE();
    }
    // near halo (rows y0-1..y0+1): tid<24 -> (side, c-octet, dy)
    {
        const int s = tid & 1, oc = (tid >> 1) & 3, dy = tid >> 3;
        const int gy = y0 - 1 + dy;
        const int gx = x0 - 1 + s * 65;
        const bool ok = (tid < 24) && ((unsigned)gy < (unsigned)HH) &&
                        ((unsigned)gx < (unsigned)WW);
        const float* q = zb + ((size_t)(oc * 8) * HH + (ok ? gy : 0)) * WW + (ok ? gx : 0);
        float t8[8];
#pragma unroll
        for (int j = 0; j < 8; ++j) t8[j] = ok ? q[(size_t)j * HH * WW] : 0.f;
        if (tid < 24)
            *(short8*)&z_lds[(dy * 66 + s * 65) * 40 + oc * 8] = pack8(t8);
        SCHED_FENCE();
    }
    // far halo (rows y0+2..y0+8): tid in [64,120) -> (side, c-octet, row)
    {
        const int fi = tid - 64;
        const int s = fi & 1, oc = (fi >> 1) & 3, fr = fi >> 3;
        const int gy = y0 + 2 + fr;
        const int gx = x0 - 1 + s * 65;
        const bool ok = (tid >= 64) && (tid < 120) && (gy < HH) &&
                        ((unsigned)gx < (unsigned)WW);
        const float* q = zb + ((size_t)(oc * 8) * HH + (ok ? gy : 0)) * WW + (ok ? gx : 0);
        float t8[8];
#pragma unroll
        for (int j = 0; j < 8; ++j) t8[j] = ok ? q[(size_t)j * HH * WW] : 0.f;
        if (tid >= 64 && tid < 120)
            *(short8*)&halo_lds[(fr * 2 + s) * 32 + oc * 8] = pack8(t8);
        SCHED_FENCE();
    }

    // hoisted biases (4 regs)
    float bias1[2], bias2[2];
#pragma unroll
    for (int nt = 0; nt < 2; ++nt) bias1[nt] = b1g[wave * 32 + nt * 16 + lr];
#pragma unroll
    for (int nt = 0; nt < 2; ++nt) bias2[nt] = b2g[nt * 16 + lr];

    BARRIER();

    const int tap_di[8] = {0, 0, 0, 1, 1, 2, 2, 2};
    const int tap_dj[8] = {0, 1, 2, 0, 2, 0, 1, 2};

    float mv8[8];   // single distance-1 prefetch buffer

#pragma unroll
    for (int r = 0; r < YS; ++r) {
        const int y = y0 + r;
        const int S0 = r & 3, S1 = (r + 1) & 3, S2 = (r + 2) & 3, S3 = (r + 3) & 3;

        // ---------- issue prefetch: row y+2 (consumed at commit, end of this iter) ----------
        if (r < 7) {
            const int gy = y + 2;
            const bool ok = gy < HH;
            const float* p = zb + ((size_t)(o * 8) * HH + (ok ? gy : 0)) * WW + x0 + l;
#pragma unroll
            for (int j = 0; j < 8; ++j) mv8[j] = ok ? p[(size_t)j * HH * WW] : 0.f;
        }
        SCHED_FENCE();

        // ---------- GEMM1: per wave M=64 (mt 0..3), N=32 quarter (nt 0..1) ----------
        f32x4 acc[4][2];
#pragma unroll
        for (int mt = 0; mt < 4; ++mt)
#pragma unroll
            for (int nt = 0; nt < 2; ++nt)
                acc[mt][nt] = (f32x4){0.f, 0.f, 0.f, 0.f};

        const int rowoff[3] = {S0 * ZROW, S1 * ZROW, S2 * ZROW};
#pragma unroll
        for (int t = 0; t < 8; ++t) {
            const int di = tap_di[t], dj = tap_dj[t];
            const int p = di * 3 + dj;
            short8 afr[4];
#pragma unroll
            for (int mt = 0; mt < 4; ++mt)
                afr[mt] = *(const short8*)&z_lds[rowoff[di] + (mt * 16 + lr + dj) * 40 + lq * 8];
            short8 bfr[2];
#pragma unroll
            for (int nt = 0; nt < 2; ++nt)
                bfr[nt] = *(const short8*)&w1t[p * (HID * KC) + (wave * 32 + nt * 16 + lr) * KC + lq * 8];
#pragma unroll
            for (int nt = 0; nt < 2; ++nt)
#pragma unroll
                for (int mt = 0; mt < 4; ++mt)
                    acc[mt][nt] = __builtin_amdgcn_mfma_f32_16x16x32_bf16(
                        afr[mt], bfr[nt], acc[mt][nt], 0, 0, 0);
        }

        // ---------- epilogue1: +b1, ReLU, bf16 -> h ----------
#pragma unroll
        for (int nt = 0; nt < 2; ++nt) {
            const int d = wave * 32 + nt * 16 + lr;
#pragma unroll
            for (int mt = 0; mt < 4; ++mt)
#pragma unroll
                for (int rr = 0; rr < 4; ++rr) {
                    float v = acc[mt][nt][rr] + bias1[nt];
                    v = v > 0.f ? v : 0.f;
                    const int m = mt * 16 + lq * 4 + rr;
                    h_lds[m * HSTR + d] = f2bf(v);
                }
        }
        BARRIER();   // h ready; all waves' GEMM1 z-reads complete

        // ---------- GEMM2: M=64, N=32, K=128 (B from L1-hot w2t) ----------
        f32x4 acc2[2];
        acc2[0] = (f32x4){0.f, 0.f, 0.f, 0.f};
        acc2[1] = (f32x4){0.f, 0.f, 0.f, 0.f};
        const int m2 = wave * 16 + lr;
#pragma unroll
        for (int k4 = 0; k4 < 4; ++k4) {
            short8 afr = *(const short8*)&h_lds[m2 * HSTR + k4 * 32 + lq * 8];
#pragma unroll
            for (int nt = 0; nt < 2; ++nt) {
                short8 bfr = *(const short8*)&w2t[(nt * 16 + lr) * HID + k4 * 32 + lq * 8];
                acc2[nt] = __builtin_amdgcn_mfma_f32_16x16x32_bf16(afr, bfr, acc2[nt], 0, 0, 0);
            }
        }

        // ---------- epilogue2: +b2, 16B coalesced stores ----------
#pragma unroll
        for (int nt = 0; nt < 2; ++nt) {
            const int kout = nt * 16 + lr;
            f32x4 pk;
#pragma unroll
            for (int rr = 0; rr < 4; ++rr) pk[rr] = acc2[nt][rr] + bias2[nt];
            const int mb = wave * 16 + lq * 4;
            const size_t off = ((size_t)(b * KC + kout) * HH + y) * WW + x0 + mb;
            *(f32x4*)&outg[off] = pk;
        }

        // ---------- commit prefetched row y+2 into slot S3 ----------
        if (r < 7) {
            *(short8*)&z_lds[(S3 * 66 + l + 1) * 40 + o * 8] = pack8(mv8);
            if (tid < 8) {
                const int side = tid & 1, oct = tid >> 1;
                short8 hv = *(const short8*)&halo_lds[(r * 2 + side) * 32 + oct * 8];
                *(short8*)&z_lds[(S3 * 66 + side * 65) * 40 + oct * 8] = hv;
            }
        }
        BARRIER();   // commit visible; h-reads done (h rewritten next iter)
    }
}

extern "C" void kernel_launch(void* const* d_in, const int* in_sizes, int n_in,
                              void* d_out, int out_size, void* d_ws, size_t ws_size,
                              hipStream_t stream)
{
    const float* z  = (const float*)d_in[0];
    const float* W1 = (const float*)d_in[1];
    const float* b1 = (const float*)d_in[2];
    const float* W2 = (const float*)d_in[3];
    const float* b2 = (const float*)d_in[4];
    float* out = (float*)d_out;
    unsigned short* w1t = (unsigned short*)d_ws;                // 73728 B
    unsigned short* w2t = (unsigned short*)d_ws + 9 * HID * KC; // + 8192 B

    hipLaunchKernelGGL(prep_weights, dim3(160), dim3(256), 0, stream, W1, W2, w1t, w2t);
    hipLaunchKernelGGL(local_pred_kernel, dim3(8 * 4 * (HH / YS)), dim3(256), 0, stream,
                       z, w1t, b1, w2t, b2, out);
}